// Round 3
// baseline (284.841 us; speedup 1.0000x reference)
//
#include <hip/hip_runtime.h>
#include <hip/hip_bf16.h>
#include <hip/hip_cooperative_groups.h>

namespace cg = cooperative_groups;

#define NNODES 20000
#define NE_RAW 200000
#define NE_TOT 220000
#define MAX1   128
#define MAX2   512
#define MAXE1  4096
#define MAXE2  256
#define FIN    1280
#define FH     1024
#define NHEAD  4
#define C2     128
#define CAPE   512
#define GRID   320
#define BLK    256
#define ROWS   32
#define KCH    160      // k-chunk length (8 chunks x 160 = 1280)
#define NKC    8
#define NCT    8        // col tiles of 128 (8 x 128 = 1024)

struct Params {
  const float* x; const int* ei; const int* mip;
  const float* msd; const float* Wm1; const float* bm1;
  const float* Wm2; const float* bm2;
  const float* W1; const float* as1; const float* ad1; const float* b1;
  const float* W2; const float* as2; const float* ad2; const float* b2;
  const float* Wp1; const float* bp1; const float* Wp2; const float* bp2;
  const float* Wp3; const float* bp3;
  float* out;
  int* cnt; int* slot1; int* slot2; int* S1; int* S2;
  int* E1s; int* E1d; int* E2;
  float* hh; float* hpart; float* gb;
  float* asrc1; float* adst1; float* r1;
};

union SMem {
  float xs[ROWS * KCH];                                   // P3 stage (20480 B); comb overlays
  float red[256];                                         // P1 pmd reduce
  struct {
    int   lsrc[CAPE]; int scnt;
    float ev[NHEAD][CAPE];
    float h1row[FH];
    float comb[C2];
  } p5;                                                   // ~14.6 KB
  struct {
    float al[MAXE2]; int jl[MAXE2];
    float feat[C2], r2s[C2], z1s[C2], z2s[32];
  } p6;
};

__global__ void __launch_bounds__(BLK) k_all(Params p){
  cg::grid_group gg = cg::this_grid();
  __shared__ SMem sm;
  const int t   = threadIdx.x;
  const int bid = blockIdx.x;
  const int gtid = bid * BLK + t;

  // ---------- P0: init slot maps + counters ----------
  for (int i = gtid; i < NNODES; i += GRID * BLK){ p.slot1[i] = -1; p.slot2[i] = -1; }
  if (gtid < 8) p.cnt[gtid] = 0;
  gg.sync();

  const int mi = p.mip[0];

  // ---------- P1: scan edges -> S1/E2 ; pmd stage-1 GEMV on blocks 0..3 ----------
  for (int e = gtid; e < NE_TOT; e += GRID * BLK){
    int src, dst;
    if (e < NE_RAW){ src = p.ei[e]; dst = p.ei[NE_RAW + e]; }
    else { src = e - NE_RAW; dst = src; }
    if (dst == mi){
      int q = atomicAdd(&p.cnt[3], 1);
      if (q < MAXE2) p.E2[q] = src;
      if (atomicCAS(&p.slot1[src], -1, -9) == -1){
        int idx = atomicAdd(&p.cnt[0], 1);
        if (idx < MAX1){ p.S1[idx] = src; p.slot1[src] = idx; }
      }
    }
  }
  if (bid < 4){
    int col = bid * 32 + (t & 31);
    int sl  = t >> 5;
    float s = 0.f;
    for (int k = sl * 128; k < sl * 128 + 128; ++k) s += p.msd[k] * p.Wm1[k * C2 + col];
    sm.red[t] = s;
    __syncthreads();
    if (t < 32){
      float v = 0.f;
      #pragma unroll
      for (int q = 0; q < 8; ++q) v += sm.red[q * 32 + t];
      v += p.bm1[col];
      p.r1[col] = v > 0.f ? v : 0.f;
    }
  }
  gg.sync();

  // ---------- P2: scan edges -> S2/E1 ----------
  for (int e = gtid; e < NE_TOT; e += GRID * BLK){
    int src, dst;
    if (e < NE_RAW){ src = p.ei[e]; dst = p.ei[NE_RAW + e]; }
    else { src = e - NE_RAW; dst = src; }
    if (p.slot1[dst] >= 0){
      int q = atomicAdd(&p.cnt[2], 1);
      if (q < MAXE1){ p.E1s[q] = src; p.E1d[q] = dst; }
      if (atomicCAS(&p.slot2[src], -1, -9) == -1){
        int idx = atomicAdd(&p.cnt[1], 1);
        if (idx < MAX2){ p.S2[idx] = src; p.slot2[src] = idx; }
      }
    }
  }
  gg.sync();

  // ---------- P3: hpart[kc][row][col] = x[S2 rows, kc]@W1[kc, coltile] ----------
  {
    int n2 = p.cnt[1]; if (n2 > MAX2) n2 = MAX2;
    int nRG = (n2 + ROWS - 1) / ROWS;
    int nT  = nRG * NKC * NCT;                 // 64 tasks per row-group
    for (int task = bid; task < nT; task += GRID){
      int rg = task >> 6, rem = task & 63;
      int kc = rem >> 3,  ct  = rem & 7;
      int r0 = rg * ROWS, k0 = kc * KCH;
      __syncthreads();
      for (int idx = t; idx < ROWS * (KCH / 4); idx += BLK){
        int r = idx / (KCH / 4), k4 = idx - r * (KCH / 4);
        float4 v = make_float4(0.f, 0.f, 0.f, 0.f);
        if (r0 + r < n2)
          v = *(const float4*)(p.x + (long)p.S2[r0 + r] * FIN + k0 + k4 * 4);
        *(float4*)(sm.xs + r * KCH + k4 * 4) = v;
      }
      __syncthreads();
      int col = t & 127, kh = t >> 7;
      float acc[ROWS];
      #pragma unroll
      for (int r = 0; r < ROWS; ++r) acc[r] = 0.f;
      const float* Wp = p.W1 + (long)(k0 + kh * 80) * FH + ct * 128 + col;
      const float* xp = sm.xs + kh * 80;
      for (int kk = 0; kk < 80; ++kk){
        float w = Wp[(long)kk * FH];
        #pragma unroll
        for (int r = 0; r < ROWS; ++r) acc[r] += xp[r * KCH + kk] * w;
      }
      __syncthreads();
      float* comb = sm.xs;                      // reuse stage buffer
      if (kh == 1){
        #pragma unroll
        for (int r = 0; r < ROWS; ++r) comb[col * 33 + r] = acc[r];
      }
      __syncthreads();
      if (kh == 0){
        float* d0 = p.hpart + ((long)kc * MAX2 + r0) * FH + ct * 128 + col;
        #pragma unroll
        for (int r = 0; r < ROWS; ++r)
          if (r0 + r < n2) d0[(long)r * FH] = acc[r] + comb[col * 33 + r];
      }
    }
  }
  gg.sync();

  // ---------- P4: hh = sum_kc hpart ; attention scalars asrc1/adst1 ----------
  {
    int n2 = p.cnt[1]; if (n2 > MAX2) n2 = MAX2;
    int head = t >> 6;
    float4 a = *(const float4*)(p.as1 + 4 * t);
    float4 d = *(const float4*)(p.ad1 + 4 * t);
    for (int i = bid; i < n2; i += GRID){
      float4 s = make_float4(0.f, 0.f, 0.f, 0.f);
      #pragma unroll
      for (int kc = 0; kc < NKC; ++kc){
        float4 v = *(const float4*)(p.hpart + ((long)kc * MAX2 + i) * FH + 4 * t);
        s.x += v.x; s.y += v.y; s.z += v.z; s.w += v.w;
      }
      *(float4*)(p.hh + (long)i * FH + 4 * t) = s;
      float ss = s.x * a.x + s.y * a.y + s.z * a.z + s.w * a.w;
      float sd = s.x * d.x + s.y * d.y + s.z * d.z + s.w * d.w;
      #pragma unroll
      for (int o = 32; o; o >>= 1){ ss += __shfl_xor(ss, o, 64); sd += __shfl_xor(sd, o, 64); }
      if ((t & 63) == 0){ p.asrc1[i * NHEAD + head] = ss; p.adst1[i * NHEAD + head] = sd; }
    }
  }
  gg.sync();

  // ---------- P5: per S1-node: softmax + aggregate (h1 row) + h1@W2 -> gb ----------
  {
    int n1  = p.cnt[0]; if (n1  > MAX1)  n1  = MAX1;
    int nE1 = p.cnt[2]; if (nE1 > MAXE1) nE1 = MAXE1;
    for (int j = bid; j < n1; j += GRID){
      int s = p.S1[j];
      __syncthreads();
      if (t == 0) sm.p5.scnt = 0;
      __syncthreads();
      for (int e = t; e < nE1; e += BLK){
        if (p.E1d[e] == s){
          int q = atomicAdd(&sm.p5.scnt, 1);
          if (q < CAPE) sm.p5.lsrc[q] = p.slot2[p.E1s[e]];
        }
      }
      __syncthreads();
      int ce = sm.p5.scnt; if (ce > CAPE) ce = CAPE;
      int w = t >> 6, lane = t & 63;
      {
        float ad = p.adst1[p.slot2[s] * NHEAD + w];
        float m = -3.4e38f;
        for (int e = lane; e < ce; e += 64){
          float v = p.asrc1[sm.p5.lsrc[e] * NHEAD + w] + ad;
          v = v >= 0.f ? v : 0.2f * v;
          sm.p5.ev[w][e] = v;
          m = fmaxf(m, v);
        }
        #pragma unroll
        for (int o = 32; o; o >>= 1) m = fmaxf(m, __shfl_xor(m, o, 64));
        float ssum = 0.f;
        for (int e = lane; e < ce; e += 64){
          float a2 = expf(sm.p5.ev[w][e] - m);
          sm.p5.ev[w][e] = a2;
          ssum += a2;
        }
        #pragma unroll
        for (int o = 32; o; o >>= 1) ssum += __shfl_xor(ssum, o, 64);
        float inv = 1.f / (ssum + 1e-16f);
        for (int e = lane; e < ce; e += 64) sm.p5.ev[w][e] *= inv;
      }
      __syncthreads();
      float4 accv = make_float4(0.f, 0.f, 0.f, 0.f);
      int hd = t >> 6;
      for (int e = 0; e < ce; ++e){
        float al = sm.p5.ev[hd][e];
        float4 hv = *(const float4*)(p.hh + (long)sm.p5.lsrc[e] * FH + 4 * t);
        accv.x += al * hv.x; accv.y += al * hv.y; accv.z += al * hv.z; accv.w += al * hv.w;
      }
      float4 bv = *(const float4*)(p.b1 + 4 * t);
      accv.x += bv.x; accv.y += bv.y; accv.z += bv.z; accv.w += bv.w;
      accv.x = accv.x > 0.f ? accv.x : 0.f;
      accv.y = accv.y > 0.f ? accv.y : 0.f;
      accv.z = accv.z > 0.f ? accv.z : 0.f;
      accv.w = accv.w > 0.f ? accv.w : 0.f;
      *(float4*)(sm.p5.h1row + 4 * t) = accv;
      __syncthreads();
      int col = t & 127, sub = t >> 7;
      float g = 0.f;
      const float* Wp = p.W2 + (long)(sub * 512) * C2 + col;
      const float* hp = sm.p5.h1row + sub * 512;
      #pragma unroll 8
      for (int k = 0; k < 512; ++k) g += hp[k] * Wp[(long)k * C2];
      if (sub == 1) sm.p5.comb[col] = g;
      __syncthreads();
      if (sub == 0) p.gb[j * C2 + col] = g + sm.p5.comb[col];
      __syncthreads();
    }
  }
  gg.sync();

  // ---------- P6: layer-2 softmax+aggregate at mi, MLP head (block 0) ----------
  if (bid == 0){
    int jmi = p.slot1[mi];
    int ne2 = p.cnt[3]; if (ne2 > MAXE2) ne2 = MAXE2;
    for (int k = t; k < ne2; k += BLK) sm.p6.jl[k] = p.slot1[p.E2[k]];
    __syncthreads();
    int w = t >> 6, lane = t & 63;
    float adv;
    {
      int c = lane * 2;
      float v = p.gb[jmi * C2 + c] * p.ad2[c] + p.gb[jmi * C2 + c + 1] * p.ad2[c + 1];
      #pragma unroll
      for (int o = 32; o; o >>= 1) v += __shfl_xor(v, o, 64);
      adv = v;
    }
    for (int k = w; k < ne2; k += 4){
      int c = lane * 2;
      int jj = sm.p6.jl[k];
      float v = p.gb[jj * C2 + c] * p.as2[c] + p.gb[jj * C2 + c + 1] * p.as2[c + 1];
      #pragma unroll
      for (int o = 32; o; o >>= 1) v += __shfl_xor(v, o, 64);
      float e0 = v + adv;
      if (lane == 0) sm.p6.al[k] = e0 >= 0.f ? e0 : 0.2f * e0;
    }
    __syncthreads();
    if (t < 64){
      float m = -3.4e38f;
      for (int k = t; k < ne2; k += 64) m = fmaxf(m, sm.p6.al[k]);
      #pragma unroll
      for (int o = 32; o; o >>= 1) m = fmaxf(m, __shfl_xor(m, o, 64));
      float s = 0.f;
      for (int k = t; k < ne2; k += 64){
        float a2 = expf(sm.p6.al[k] - m);
        sm.p6.al[k] = a2;
        s += a2;
      }
      #pragma unroll
      for (int o = 32; o; o >>= 1) s += __shfl_xor(s, o, 64);
      float inv = 1.f / (s + 1e-16f);
      for (int k = t; k < ne2; k += 64) sm.p6.al[k] *= inv;
    }
    __syncthreads();
    if (t < C2){
      float acc = 0.f;
      for (int k = 0; k < ne2; ++k) acc += sm.p6.al[k] * p.gb[sm.p6.jl[k] * C2 + t];
      float v = acc + p.b2[t];
      sm.p6.feat[t] = v > 0.f ? v : 0.f;
      float pr = 0.f;
      for (int k = 0; k < C2; ++k) pr += p.r1[k] * p.Wm2[k * C2 + t];
      sm.p6.r2s[t] = pr + p.bm2[t];
    }
    __syncthreads();
    if (t < C2){
      float acc = 0.f;
      for (int k = 0; k < C2; ++k) acc += sm.p6.feat[k] * p.Wp1[k * C2 + t];
      for (int k = 0; k < C2; ++k) acc += sm.p6.r2s[k] * p.Wp1[(C2 + k) * C2 + t];
      float v = acc + p.bp1[t];
      sm.p6.z1s[t] = v > 0.f ? v : 0.f;
    }
    __syncthreads();
    if (t < 32){
      float acc = 0.f;
      for (int k = 0; k < C2; ++k) acc += sm.p6.z1s[k] * p.Wp2[k * 32 + t];
      float v = acc + p.bp2[t];
      sm.p6.z2s[t] = v > 0.f ? v : 0.f;
    }
    __syncthreads();
    if (t == 0){
      float acc = 0.f;
      for (int k = 0; k < 32; ++k) acc += sm.p6.z2s[k] * p.Wp3[k];
      p.out[0] = acc + p.bp3[0];
    }
  }
}

extern "C" void kernel_launch(void* const* d_in, const int* in_sizes, int n_in,
                              void* d_out, int out_size, void* d_ws, size_t ws_size,
                              hipStream_t stream){
  Params P;
  P.x   = (const float*)d_in[0];
  P.ei  = (const int*)d_in[1];
  P.mip = (const int*)d_in[2];
  P.msd = (const float*)d_in[3];
  P.Wm1 = (const float*)d_in[4];
  P.bm1 = (const float*)d_in[5];
  P.Wm2 = (const float*)d_in[6];
  P.bm2 = (const float*)d_in[7];
  P.W1  = (const float*)d_in[8];
  P.as1 = (const float*)d_in[9];
  P.ad1 = (const float*)d_in[10];
  P.b1  = (const float*)d_in[11];
  P.W2  = (const float*)d_in[12];
  P.as2 = (const float*)d_in[13];
  P.ad2 = (const float*)d_in[14];
  P.b2  = (const float*)d_in[15];
  P.Wp1 = (const float*)d_in[16];
  P.bp1 = (const float*)d_in[17];
  P.Wp2 = (const float*)d_in[18];
  P.bp2 = (const float*)d_in[19];
  P.Wp3 = (const float*)d_in[20];
  P.bp3 = (const float*)d_in[21];
  P.out = (float*)d_out;

  char* q = (char*)d_ws;
  auto alloc = [&](size_t bytes) -> void* {
    void* r = (void*)q;
    q += (bytes + 255) & ~(size_t)255;
    return r;
  };
  P.cnt   = (int*)alloc(8 * 4);
  P.slot1 = (int*)alloc(NNODES * 4);
  P.slot2 = (int*)alloc(NNODES * 4);
  P.S1    = (int*)alloc(MAX1 * 4);
  P.S2    = (int*)alloc(MAX2 * 4);
  P.E1s   = (int*)alloc(MAXE1 * 4);
  P.E1d   = (int*)alloc(MAXE1 * 4);
  P.E2    = (int*)alloc(MAXE2 * 4);
  P.hh    = (float*)alloc((size_t)MAX2 * FH * 4);                 // 2 MB
  P.hpart = (float*)alloc((size_t)NKC * MAX2 * FH * 4);           // 16.8 MB
  P.gb    = (float*)alloc(MAX1 * C2 * 4);
  P.asrc1 = (float*)alloc(MAX2 * NHEAD * 4);
  P.adst1 = (float*)alloc(MAX2 * NHEAD * 4);
  P.r1    = (float*)alloc(C2 * 4);

  void* kargs[] = { (void*)&P };
  hipLaunchCooperativeKernel((const void*)k_all, dim3(GRID), dim3(BLK),
                             kargs, 0, stream);
}

// Round 4
// 101.498 us; speedup vs baseline: 2.8064x; 2.8064x over previous
//
#include <hip/hip_runtime.h>
#include <hip/hip_bf16.h>

#define NNODES 20000
#define NE_RAW 200000
#define NE_TOT 220000
#define MAX1   128
#define MAX2   512
#define MAXE1  4096
#define MAXE2  256
#define FIN    1280
#define FH     1024
#define HC     256
#define NHEAD  4
#define C2     128
#define CAPE   512
#define NKC    8        // k-chunks of 160
#define KCH    160
#define NCT    8        // col tiles of 128
#define RG     64       // rows per group
#define HH_GEMM_BLOCKS 192

__device__ __forceinline__ float lrelu(float x){ return x >= 0.f ? x : 0.2f * x; }

// K0: reset slot maps + counters
__global__ void k_init(int* cnt, int* slot1, int* slot2){
  int i = blockIdx.x * 256 + threadIdx.x;
  if (i < NNODES){ slot1[i] = -1; slot2[i] = -1; }
  if (i < 8) cnt[i] = 0;
}

// K1: S1 = in-neighbors of mutation_idx (incl. self-loop), E2 = edges into mi
__global__ void k_scan1(const int* __restrict__ ei, const int* __restrict__ mip,
                        int* cnt, int* slot1, int* S1, int* E2){
  int e = blockIdx.x * 256 + threadIdx.x;
  if (e >= NE_TOT) return;
  int mi = mip[0];
  int src, dst;
  if (e < NE_RAW){ src = ei[e]; dst = ei[NE_RAW + e]; }
  else { src = e - NE_RAW; dst = src; }
  if (dst != mi) return;
  int p = atomicAdd(&cnt[3], 1);
  if (p < MAXE2) E2[p] = src;
  if (atomicCAS(&slot1[src], -1, -9) == -1){
    int idx = atomicAdd(&cnt[0], 1);
    if (idx < MAX1){ S1[idx] = src; slot1[src] = idx; }
  }
}

// K2: S2 = in-neighbors of S1; E1 = edge occurrences into S1
__global__ void k_scan2(const int* __restrict__ ei, int* cnt,
                        const int* __restrict__ slot1, int* slot2,
                        int* S2, int* E1s, int* E1d){
  int e = blockIdx.x * 256 + threadIdx.x;
  if (e >= NE_TOT) return;
  int src, dst;
  if (e < NE_RAW){ src = ei[e]; dst = ei[NE_RAW + e]; }
  else { src = e - NE_RAW; dst = src; }
  if (slot1[dst] < 0) return;
  int p = atomicAdd(&cnt[2], 1);
  if (p < MAXE1){ E1s[p] = src; E1d[p] = dst; }
  if (atomicCAS(&slot2[src], -1, -9) == -1){
    int idx = atomicAdd(&cnt[1], 1);
    if (idx < MAX2){ S2[idx] = src; slot2[src] = idx; }
  }
}

// K3: hpart[kc][row][ct*128+col] = x[S2 rows, kc-chunk] @ W1[kc-chunk, ct-slice]
//     No atomics, no pre-zero: every (kc,row,col) written exactly once.
//     Blocks HH_GEMM_BLOCKS.. : pmd stage-1 GEMV r1 = relu(msd@Wm1+bm1)
__global__ __launch_bounds__(256) void k_hh(
    const float* __restrict__ x, const float* __restrict__ W1,
    const float* __restrict__ msd, const float* __restrict__ Wm1,
    const float* __restrict__ bm1,
    const int* __restrict__ cnt, const int* __restrict__ S2,
    float* __restrict__ hpart, float* __restrict__ r1){
  int t = threadIdx.x;
  if (blockIdx.x >= HH_GEMM_BLOCKS){
    __shared__ float red[256];
    int b   = blockIdx.x - HH_GEMM_BLOCKS;   // 0..3 -> 32 cols each
    int col = b * 32 + (t & 31);
    int sl  = t >> 5;                        // 8 k-slices of 128
    float s = 0.f;
    for (int k = sl * 128; k < sl * 128 + 128; ++k)
      s += msd[k] * Wm1[k * C2 + col];
    red[t] = s;
    __syncthreads();
    if (t < 32){
      float v = 0.f;
      #pragma unroll
      for (int q = 0; q < 8; ++q) v += red[q * 32 + t];
      v += bm1[col];
      r1[col] = v > 0.f ? v : 0.f;
    }
    return;
  }
  __shared__ float xs[RG * KCH];             // 40 KB
  int n2 = cnt[1]; if (n2 > MAX2) n2 = MAX2;
  int nRG = (n2 + RG - 1) / RG;
  int nT  = nRG * NKC * NCT;                 // 64 tasks per row-group
  for (int task = blockIdx.x; task < nT; task += HH_GEMM_BLOCKS){
    int rg = task >> 6, rem = task & 63;
    int kc = rem >> 3,  ct  = rem & 7;
    int r0 = rg * RG,   k0  = kc * KCH;
    __syncthreads();
    for (int idx = t; idx < RG * (KCH / 4); idx += 256){
      int r = idx / (KCH / 4), k4 = idx - r * (KCH / 4);
      float4 v = make_float4(0.f, 0.f, 0.f, 0.f);
      if (r0 + r < n2)
        v = *(const float4*)(x + (long)S2[r0 + r] * FIN + k0 + k4 * 4);
      *(float4*)(xs + r * KCH + k4 * 4) = v;
    }
    __syncthreads();
    int col = t & 127, rh = t >> 7;          // rh: which 32-row half
    float acc[32];
    #pragma unroll
    for (int r = 0; r < 32; ++r) acc[r] = 0.f;
    const float* Wp = W1 + (long)k0 * FH + ct * 128 + col;
    const float* xp = xs + rh * 32 * KCH;
    #pragma unroll 4
    for (int kk = 0; kk < KCH; ++kk){
      float w = Wp[(long)kk * FH];
      #pragma unroll
      for (int r = 0; r < 32; ++r) acc[r] += xp[r * KCH + kk] * w;
    }
    float* d0 = hpart + ((long)kc * MAX2 + r0 + rh * 32) * FH + ct * 128 + col;
    #pragma unroll
    for (int r = 0; r < 32; ++r)
      if (r0 + rh * 32 + r < n2) d0[(long)r * FH] = acc[r];
  }
}

// K4: hh = sum_kc hpart ; attention scalars asrc1/adst1 (one block per S2 row)
__global__ void k_ascal(const float* __restrict__ hpart,
                        const float* __restrict__ as1, const float* __restrict__ ad1,
                        const int* __restrict__ cnt,
                        float* __restrict__ hh,
                        float* __restrict__ asrc1, float* __restrict__ adst1){
  int t = threadIdx.x, head = t >> 6;
  int n2 = cnt[1]; if (n2 > MAX2) n2 = MAX2;
  float4 a = *(const float4*)(as1 + 4 * t);
  float4 d = *(const float4*)(ad1 + 4 * t);
  for (int i = blockIdx.x; i < n2; i += gridDim.x){
    float4 s = make_float4(0.f, 0.f, 0.f, 0.f);
    #pragma unroll
    for (int kc = 0; kc < NKC; ++kc){
      float4 v = *(const float4*)(hpart + ((long)kc * MAX2 + i) * FH + 4 * t);
      s.x += v.x; s.y += v.y; s.z += v.z; s.w += v.w;
    }
    *(float4*)(hh + (long)i * FH + 4 * t) = s;
    float ss = s.x * a.x + s.y * a.y + s.z * a.z + s.w * a.w;
    float sd = s.x * d.x + s.y * d.y + s.z * d.z + s.w * d.w;
    #pragma unroll
    for (int o = 32; o; o >>= 1){ ss += __shfl_xor(ss, o, 64); sd += __shfl_xor(sd, o, 64); }
    if ((t & 63) == 0){ asrc1[i * NHEAD + head] = ss; adst1[i * NHEAD + head] = sd; }
  }
}

// K5: per S1-node: layer-1 softmax + aggregate -> h1row (LDS) -> h1row@W2 -> gb
__global__ void k_agg1(const float* __restrict__ hh,
                       const float* __restrict__ asrc1, const float* __restrict__ adst1,
                       const float* __restrict__ b1, const float* __restrict__ W2,
                       const int* __restrict__ cnt, const int* __restrict__ S1,
                       const int* __restrict__ slot2,
                       const int* __restrict__ E1s, const int* __restrict__ E1d,
                       float* __restrict__ gb){
  __shared__ int   lsrc[CAPE];
  __shared__ float ev[NHEAD][CAPE];
  __shared__ float h1row[FH];
  __shared__ float comb[C2];
  __shared__ int   scnt;
  int t = threadIdx.x;
  int n1  = cnt[0]; if (n1  > MAX1)  n1  = MAX1;
  int nE1 = cnt[2]; if (nE1 > MAXE1) nE1 = MAXE1;
  for (int j = blockIdx.x; j < n1; j += gridDim.x){
    int s = S1[j];
    __syncthreads();
    if (t == 0) scnt = 0;
    __syncthreads();
    for (int e = t; e < nE1; e += 256){
      if (E1d[e] == s){
        int q = atomicAdd(&scnt, 1);
        if (q < CAPE) lsrc[q] = slot2[E1s[e]];
      }
    }
    __syncthreads();
    int ce = scnt; if (ce > CAPE) ce = CAPE;
    int w = t >> 6, lane = t & 63;
    {
      float ad = adst1[slot2[s] * NHEAD + w];
      float m = -3.4e38f;
      for (int e = lane; e < ce; e += 64){
        float v = lrelu(asrc1[lsrc[e] * NHEAD + w] + ad);
        ev[w][e] = v;
        m = fmaxf(m, v);
      }
      #pragma unroll
      for (int o = 32; o; o >>= 1) m = fmaxf(m, __shfl_xor(m, o, 64));
      float ssum = 0.f;
      for (int e = lane; e < ce; e += 64){
        float a2 = expf(ev[w][e] - m);
        ev[w][e] = a2;
        ssum += a2;
      }
      #pragma unroll
      for (int o = 32; o; o >>= 1) ssum += __shfl_xor(ssum, o, 64);
      float inv = 1.f / (ssum + 1e-16f);
      for (int e = lane; e < ce; e += 64) ev[w][e] *= inv;
    }
    __syncthreads();
    float4 accv = make_float4(0.f, 0.f, 0.f, 0.f);
    int hd = t >> 6;
    for (int e = 0; e < ce; ++e){
      float al = ev[hd][e];
      float4 hv = *(const float4*)(hh + (long)lsrc[e] * FH + 4 * t);
      accv.x += al * hv.x; accv.y += al * hv.y; accv.z += al * hv.z; accv.w += al * hv.w;
    }
    float4 bv = *(const float4*)(b1 + 4 * t);
    accv.x += bv.x; accv.y += bv.y; accv.z += bv.z; accv.w += bv.w;
    accv.x = accv.x > 0.f ? accv.x : 0.f;
    accv.y = accv.y > 0.f ? accv.y : 0.f;
    accv.z = accv.z > 0.f ? accv.z : 0.f;
    accv.w = accv.w > 0.f ? accv.w : 0.f;
    *(float4*)(h1row + 4 * t) = accv;
    __syncthreads();
    int col = t & 127, sub = t >> 7;
    float g = 0.f;
    const float* Wp = W2 + (long)(sub * 512) * C2 + col;
    const float* hp = h1row + sub * 512;
    #pragma unroll 8
    for (int k = 0; k < 512; ++k) g += hp[k] * Wp[(long)k * C2];
    if (sub == 1) comb[col] = g;
    __syncthreads();
    if (sub == 0) gb[j * C2 + col] = g + comb[col];
    __syncthreads();
  }
}

// K6: layer-2 attention + softmax + aggregate at mi, then MLP head -> scalar
__global__ void k_final(const int* __restrict__ mip, const int* __restrict__ cnt,
                        const int* __restrict__ slot1, const int* __restrict__ E2,
                        const float* __restrict__ gb,
                        const float* __restrict__ as2, const float* __restrict__ ad2,
                        const float* __restrict__ b2,
                        const float* __restrict__ r1,
                        const float* __restrict__ Wm2, const float* __restrict__ bm2,
                        const float* __restrict__ Wp1, const float* __restrict__ bp1,
                        const float* __restrict__ Wp2, const float* __restrict__ bp2,
                        const float* __restrict__ Wp3, const float* __restrict__ bp3,
                        float* __restrict__ out){
  __shared__ float al[MAXE2];
  __shared__ int   jl[MAXE2];
  __shared__ float feat[C2], r2s[C2], z1s[C2], z2s[32];
  int t = threadIdx.x;
  int mi  = mip[0];
  int jmi = slot1[mi];
  int ne2 = cnt[3]; if (ne2 > MAXE2) ne2 = MAXE2;
  for (int k = t; k < ne2; k += 256) jl[k] = slot1[E2[k]];
  __syncthreads();
  int w = t >> 6, lane = t & 63;
  float adv;
  {
    int c = lane * 2;
    float v = gb[jmi * C2 + c] * ad2[c] + gb[jmi * C2 + c + 1] * ad2[c + 1];
    #pragma unroll
    for (int o = 32; o; o >>= 1) v += __shfl_xor(v, o, 64);
    adv = v;
  }
  for (int k = w; k < ne2; k += 4){
    int c = lane * 2;
    int jj = jl[k];
    float v = gb[jj * C2 + c] * as2[c] + gb[jj * C2 + c + 1] * as2[c + 1];
    #pragma unroll
    for (int o = 32; o; o >>= 1) v += __shfl_xor(v, o, 64);
    if (lane == 0) al[k] = lrelu(v + adv);
  }
  __syncthreads();
  if (t < 64){
    float m = -3.4e38f;
    for (int k = t; k < ne2; k += 64) m = fmaxf(m, al[k]);
    #pragma unroll
    for (int o = 32; o; o >>= 1) m = fmaxf(m, __shfl_xor(m, o, 64));
    float s = 0.f;
    for (int k = t; k < ne2; k += 64){
      float a2 = expf(al[k] - m);
      al[k] = a2;
      s += a2;
    }
    #pragma unroll
    for (int o = 32; o; o >>= 1) s += __shfl_xor(s, o, 64);
    float inv = 1.f / (s + 1e-16f);
    for (int k = t; k < ne2; k += 64) al[k] *= inv;
  }
  __syncthreads();
  if (t < C2){
    float acc = 0.f;
    for (int k = 0; k < ne2; ++k) acc += al[k] * gb[jl[k] * C2 + t];
    float v = acc + b2[t];
    feat[t] = v > 0.f ? v : 0.f;
    float pr = 0.f;
    for (int k = 0; k < C2; ++k) pr += r1[k] * Wm2[k * C2 + t];
    r2s[t] = pr + bm2[t];
  }
  __syncthreads();
  if (t < C2){
    float acc = 0.f;
    for (int k = 0; k < C2; ++k) acc += feat[k] * Wp1[k * C2 + t];
    for (int k = 0; k < C2; ++k) acc += r2s[k] * Wp1[(C2 + k) * C2 + t];
    float v = acc + bp1[t];
    z1s[t] = v > 0.f ? v : 0.f;
  }
  __syncthreads();
  if (t < 32){
    float acc = 0.f;
    for (int k = 0; k < C2; ++k) acc += z1s[k] * Wp2[k * 32 + t];
    float v = acc + bp2[t];
    z2s[t] = v > 0.f ? v : 0.f;
  }
  __syncthreads();
  if (t == 0){
    float acc = 0.f;
    for (int k = 0; k < 32; ++k) acc += z2s[k] * Wp3[k];
    out[0] = acc + bp3[0];
  }
}

extern "C" void kernel_launch(void* const* d_in, const int* in_sizes, int n_in,
                              void* d_out, int out_size, void* d_ws, size_t ws_size,
                              hipStream_t stream){
  const float* x   = (const float*)d_in[0];
  const int*   ei  = (const int*)d_in[1];
  const int*   mip = (const int*)d_in[2];
  const float* msd = (const float*)d_in[3];
  const float* Wm1 = (const float*)d_in[4];
  const float* bm1 = (const float*)d_in[5];
  const float* Wm2 = (const float*)d_in[6];
  const float* bm2 = (const float*)d_in[7];
  const float* W1  = (const float*)d_in[8];
  const float* as1 = (const float*)d_in[9];
  const float* ad1 = (const float*)d_in[10];
  const float* b1  = (const float*)d_in[11];
  const float* W2  = (const float*)d_in[12];
  const float* as2 = (const float*)d_in[13];
  const float* ad2 = (const float*)d_in[14];
  const float* b2  = (const float*)d_in[15];
  const float* Wp1 = (const float*)d_in[16];
  const float* bp1 = (const float*)d_in[17];
  const float* Wp2 = (const float*)d_in[18];
  const float* bp2 = (const float*)d_in[19];
  const float* Wp3 = (const float*)d_in[20];
  const float* bp3 = (const float*)d_in[21];
  float* out = (float*)d_out;

  char* q = (char*)d_ws;
  auto alloc = [&](size_t bytes) -> void* {
    void* r = (void*)q;
    q += (bytes + 255) & ~(size_t)255;
    return r;
  };
  int* cnt   = (int*)alloc(8 * 4);
  int* slot1 = (int*)alloc(NNODES * 4);
  int* slot2 = (int*)alloc(NNODES * 4);
  int* S1    = (int*)alloc(MAX1 * 4);
  int* S2    = (int*)alloc(MAX2 * 4);
  int* E1s   = (int*)alloc(MAXE1 * 4);
  int* E1d   = (int*)alloc(MAXE1 * 4);
  int* E2    = (int*)alloc(MAXE2 * 4);
  float* hpart = (float*)alloc((size_t)NKC * MAX2 * FH * 4);   // 16.8 MB
  float* hh    = (float*)alloc((size_t)MAX2 * FH * 4);         // 2 MB
  float* gb    = (float*)alloc(MAX1 * C2 * 4);
  float* asrc1 = (float*)alloc(MAX2 * NHEAD * 4);
  float* adst1 = (float*)alloc(MAX2 * NHEAD * 4);
  float* r1    = (float*)alloc(C2 * 4);

  k_init <<<(NNODES + 255) / 256, 256, 0, stream>>>(cnt, slot1, slot2);
  k_scan1<<<(NE_TOT + 255) / 256, 256, 0, stream>>>(ei, mip, cnt, slot1, S1, E2);
  k_scan2<<<(NE_TOT + 255) / 256, 256, 0, stream>>>(ei, cnt, slot1, slot2, S2, E1s, E1d);
  k_hh   <<<HH_GEMM_BLOCKS + 4, 256, 0, stream>>>(x, W1, msd, Wm1, bm1, cnt, S2, hpart, r1);
  k_ascal<<<128, 256, 0, stream>>>(hpart, as1, ad1, cnt, hh, asrc1, adst1);
  k_agg1 <<<32, 256, 0, stream>>>(hh, asrc1, adst1, b1, W2, cnt, S1, slot2, E1s, E1d, gb);
  k_final<<<1, 256, 0, stream>>>(mip, cnt, slot1, E2, gb, as2, ad2, b2, r1,
                                 Wm2, bm2, Wp1, bp1, Wp2, bp2, Wp3, bp3, out);
}

// Round 5
// 86.234 us; speedup vs baseline: 3.3031x; 1.1770x over previous
//
#include <hip/hip_runtime.h>
#include <hip/hip_bf16.h>

#define NNODES 20000
#define NE_RAW 200000
#define NE_TOT 220000
#define MAX1   128
#define MAX2   512
#define MAXE1  4096
#define MAXE2  256
#define FIN    1280
#define FH     1024
#define HC     256
#define NHEAD  4
#define C2     128
#define CAPE   512
#define KCK    64       // k per chunk
#define NKC    20       // 20 x 64 = 1280
#define HH_GEMM_BLOCKS 320   // 20 kc x 8 ct x 2 row-splits

__device__ __forceinline__ float lrelu(float x){ return x >= 0.f ? x : 0.2f * x; }

// K0: reset slot maps + counters
__global__ void k_init(int* cnt, int* slot1, int* slot2){
  int i = blockIdx.x * 256 + threadIdx.x;
  if (i < NNODES){ slot1[i] = -1; slot2[i] = -1; }
  if (i < 8) cnt[i] = 0;
}

// K1: S1 = in-neighbors of mutation_idx (incl. self-loop), E2 = edges into mi
__global__ void k_scan1(const int* __restrict__ ei, const int* __restrict__ mip,
                        int* cnt, int* slot1, int* S1, int* E2){
  int e = blockIdx.x * 256 + threadIdx.x;
  if (e >= NE_TOT) return;
  int mi = mip[0];
  int src, dst;
  if (e < NE_RAW){ src = ei[e]; dst = ei[NE_RAW + e]; }
  else { src = e - NE_RAW; dst = src; }
  if (dst != mi) return;
  int p = atomicAdd(&cnt[3], 1);
  if (p < MAXE2) E2[p] = src;
  if (atomicCAS(&slot1[src], -1, -9) == -1){
    int idx = atomicAdd(&cnt[0], 1);
    if (idx < MAX1){ S1[idx] = src; slot1[src] = idx; }
  }
}

// K2: S2 = in-neighbors of S1; E1 = edge occurrences into S1
__global__ void k_scan2(const int* __restrict__ ei, int* cnt,
                        const int* __restrict__ slot1, int* slot2,
                        int* S2, int* E1s, int* E1d){
  int e = blockIdx.x * 256 + threadIdx.x;
  if (e >= NE_TOT) return;
  int src, dst;
  if (e < NE_RAW){ src = ei[e]; dst = ei[NE_RAW + e]; }
  else { src = e - NE_RAW; dst = src; }
  if (slot1[dst] < 0) return;
  int p = atomicAdd(&cnt[2], 1);
  if (p < MAXE1){ E1s[p] = src; E1d[p] = dst; }
  if (atomicCAS(&slot2[src], -1, -9) == -1){
    int idx = atomicAdd(&cnt[1], 1);
    if (idx < MAX2){ S2[idx] = src; slot2[src] = idx; }
  }
}

// K3: LDS-tiled pruned GEMM. Block = (kc, ct, rs). W-tile [64k x 128c] staged once
// (32 KB), x-tile transposed [64k x 32r] per row-group (8 KB). Inner loop:
// 2 x ds_read_b128 + 16 FMA per k. hpart written exactly once per (kc,row,col).
// Blocks HH_GEMM_BLOCKS.. : pmd stage-1 GEMV r1 = relu(msd@Wm1+bm1).
__global__ __launch_bounds__(256) void k_hh(
    const float* __restrict__ x, const float* __restrict__ W1,
    const float* __restrict__ msd, const float* __restrict__ Wm1,
    const float* __restrict__ bm1,
    const int* __restrict__ cnt, const int* __restrict__ S2,
    float* __restrict__ hpart, float* __restrict__ r1){
  int t = threadIdx.x;
  if (blockIdx.x >= HH_GEMM_BLOCKS){
    __shared__ float red[256];
    int b   = blockIdx.x - HH_GEMM_BLOCKS;   // 0..3 -> 32 cols each
    int col = b * 32 + (t & 31);
    int sl  = t >> 5;                        // 8 k-slices of 128
    float s = 0.f;
    for (int k = sl * 128; k < sl * 128 + 128; ++k)
      s += msd[k] * Wm1[k * C2 + col];
    red[t] = s;
    __syncthreads();
    if (t < 32){
      float v = 0.f;
      #pragma unroll
      for (int q = 0; q < 8; ++q) v += red[q * 32 + t];
      v += bm1[col];
      r1[col] = v > 0.f ? v : 0.f;
    }
    return;
  }
  __shared__ float Wl[KCK][128];   // 32 KB
  __shared__ float Xl[KCK][32];    // 8 KB, transposed: [k][row]
  int bid = blockIdx.x;
  int rs = bid & 1, ct = (bid >> 1) & 7, kc = bid >> 4;
  int k0 = kc * KCK, c0 = ct * 128;
  int n2 = cnt[1]; if (n2 > MAX2) n2 = MAX2;
  // stage W tile once: 64 rows x 128 cols = 2048 float4
  for (int idx = t; idx < 2048; idx += 256){
    int r = idx >> 5, c4 = idx & 31;
    *(float4*)&Wl[r][c4 * 4] = *(const float4*)(W1 + (long)(k0 + r) * FH + c0 + c4 * 4);
  }
  int nRG = (n2 + 31) >> 5;
  int cth = t & 31, rth = t >> 5;
  for (int rg = rs; rg < nRG; rg += 2){
    int r0 = rg * 32;
    __syncthreads();                          // W ready (1st iter); Xl free (later)
    // scatter-stage x: idx -> (row = idx&31, kq = idx>>5); conflict-free LDS writes
    for (int idx = t; idx < 512; idx += 256){
      int r = idx & 31, kq = idx >> 5;
      float4 v = make_float4(0.f, 0.f, 0.f, 0.f);
      if (r0 + r < n2)
        v = *(const float4*)(x + (long)S2[r0 + r] * FIN + k0 + kq * 4);
      Xl[kq * 4 + 0][r] = v.x;
      Xl[kq * 4 + 1][r] = v.y;
      Xl[kq * 4 + 2][r] = v.z;
      Xl[kq * 4 + 3][r] = v.w;
    }
    __syncthreads();
    float4 a0 = make_float4(0.f,0.f,0.f,0.f), a1 = a0, a2 = a0, a3 = a0;
    #pragma unroll 4
    for (int k = 0; k < KCK; ++k){
      float4 w  = *(const float4*)&Wl[k][cth * 4];
      float4 xv = *(const float4*)&Xl[k][rth * 4];
      a0.x += xv.x * w.x; a0.y += xv.x * w.y; a0.z += xv.x * w.z; a0.w += xv.x * w.w;
      a1.x += xv.y * w.x; a1.y += xv.y * w.y; a1.z += xv.y * w.z; a1.w += xv.y * w.w;
      a2.x += xv.z * w.x; a2.y += xv.z * w.y; a2.z += xv.z * w.z; a2.w += xv.z * w.w;
      a3.x += xv.w * w.x; a3.y += xv.w * w.y; a3.z += xv.w * w.z; a3.w += xv.w * w.w;
    }
    int rb = r0 + rth * 4;
    float* dp = hpart + ((long)kc * MAX2 + rb) * FH + c0 + cth * 4;
    if (rb + 0 < n2) *(float4*)(dp)            = a0;
    if (rb + 1 < n2) *(float4*)(dp + FH)       = a1;
    if (rb + 2 < n2) *(float4*)(dp + 2L * FH)  = a2;
    if (rb + 3 < n2) *(float4*)(dp + 3L * FH)  = a3;
  }
}

// K4: hh = sum_kc hpart ; attention scalars asrc1/adst1 (one block per S2 row)
__global__ void k_ascal(const float* __restrict__ hpart,
                        const float* __restrict__ as1, const float* __restrict__ ad1,
                        const int* __restrict__ cnt,
                        float* __restrict__ hh,
                        float* __restrict__ asrc1, float* __restrict__ adst1){
  int t = threadIdx.x, head = t >> 6;
  int n2 = cnt[1]; if (n2 > MAX2) n2 = MAX2;
  float4 a = *(const float4*)(as1 + 4 * t);
  float4 d = *(const float4*)(ad1 + 4 * t);
  for (int i = blockIdx.x; i < n2; i += gridDim.x){
    float4 s = make_float4(0.f, 0.f, 0.f, 0.f);
    #pragma unroll
    for (int kc = 0; kc < NKC; ++kc){
      float4 v = *(const float4*)(hpart + ((long)kc * MAX2 + i) * FH + 4 * t);
      s.x += v.x; s.y += v.y; s.z += v.z; s.w += v.w;
    }
    *(float4*)(hh + (long)i * FH + 4 * t) = s;
    float ss = s.x * a.x + s.y * a.y + s.z * a.z + s.w * a.w;
    float sd = s.x * d.x + s.y * d.y + s.z * d.z + s.w * d.w;
    #pragma unroll
    for (int o = 32; o; o >>= 1){ ss += __shfl_xor(ss, o, 64); sd += __shfl_xor(sd, o, 64); }
    if ((t & 63) == 0){ asrc1[i * NHEAD + head] = ss; adst1[i * NHEAD + head] = sd; }
  }
}

// K5: per S1-node: layer-1 softmax + aggregate -> h1row (LDS) -> h1row@W2 -> gb
__global__ void k_agg1(const float* __restrict__ hh,
                       const float* __restrict__ asrc1, const float* __restrict__ adst1,
                       const float* __restrict__ b1, const float* __restrict__ W2,
                       const int* __restrict__ cnt, const int* __restrict__ S1,
                       const int* __restrict__ slot2,
                       const int* __restrict__ E1s, const int* __restrict__ E1d,
                       float* __restrict__ gb){
  __shared__ int   lsrc[CAPE];
  __shared__ float ev[NHEAD][CAPE];
  __shared__ float h1row[FH];
  __shared__ float comb[C2];
  __shared__ int   scnt;
  int t = threadIdx.x;
  int n1  = cnt[0]; if (n1  > MAX1)  n1  = MAX1;
  int nE1 = cnt[2]; if (nE1 > MAXE1) nE1 = MAXE1;
  for (int j = blockIdx.x; j < n1; j += gridDim.x){
    int s = S1[j];
    __syncthreads();
    if (t == 0) scnt = 0;
    __syncthreads();
    for (int e = t; e < nE1; e += 256){
      if (E1d[e] == s){
        int q = atomicAdd(&scnt, 1);
        if (q < CAPE) lsrc[q] = slot2[E1s[e]];
      }
    }
    __syncthreads();
    int ce = scnt; if (ce > CAPE) ce = CAPE;
    int w = t >> 6, lane = t & 63;
    {
      float ad = adst1[slot2[s] * NHEAD + w];
      float m = -3.4e38f;
      for (int e = lane; e < ce; e += 64){
        float v = lrelu(asrc1[lsrc[e] * NHEAD + w] + ad);
        ev[w][e] = v;
        m = fmaxf(m, v);
      }
      #pragma unroll
      for (int o = 32; o; o >>= 1) m = fmaxf(m, __shfl_xor(m, o, 64));
      float ssum = 0.f;
      for (int e = lane; e < ce; e += 64){
        float a2 = expf(ev[w][e] - m);
        ev[w][e] = a2;
        ssum += a2;
      }
      #pragma unroll
      for (int o = 32; o; o >>= 1) ssum += __shfl_xor(ssum, o, 64);
      float inv = 1.f / (ssum + 1e-16f);
      for (int e = lane; e < ce; e += 64) ev[w][e] *= inv;
    }
    __syncthreads();
    float4 accv = make_float4(0.f, 0.f, 0.f, 0.f);
    int hd = t >> 6;
    int e = 0;
    for (; e + 1 < ce; e += 2){
      float al0 = ev[hd][e], al1 = ev[hd][e + 1];
      float4 h0 = *(const float4*)(hh + (long)lsrc[e] * FH + 4 * t);
      float4 h1 = *(const float4*)(hh + (long)lsrc[e + 1] * FH + 4 * t);
      accv.x += al0 * h0.x + al1 * h1.x;
      accv.y += al0 * h0.y + al1 * h1.y;
      accv.z += al0 * h0.z + al1 * h1.z;
      accv.w += al0 * h0.w + al1 * h1.w;
    }
    if (e < ce){
      float al0 = ev[hd][e];
      float4 h0 = *(const float4*)(hh + (long)lsrc[e] * FH + 4 * t);
      accv.x += al0 * h0.x; accv.y += al0 * h0.y;
      accv.z += al0 * h0.z; accv.w += al0 * h0.w;
    }
    float4 bv = *(const float4*)(b1 + 4 * t);
    accv.x += bv.x; accv.y += bv.y; accv.z += bv.z; accv.w += bv.w;
    accv.x = accv.x > 0.f ? accv.x : 0.f;
    accv.y = accv.y > 0.f ? accv.y : 0.f;
    accv.z = accv.z > 0.f ? accv.z : 0.f;
    accv.w = accv.w > 0.f ? accv.w : 0.f;
    *(float4*)(h1row + 4 * t) = accv;
    __syncthreads();
    int col = t & 127, sub = t >> 7;
    float g = 0.f;
    const float* Wp = W2 + (long)(sub * 512) * C2 + col;
    const float* hp = h1row + sub * 512;
    #pragma unroll 8
    for (int k = 0; k < 512; ++k) g += hp[k] * Wp[(long)k * C2];
    if (sub == 1) comb[col] = g;
    __syncthreads();
    if (sub == 0) gb[j * C2 + col] = g + comb[col];
    __syncthreads();
  }
}

// K6: layer-2 attention + softmax + aggregate at mi, then MLP head -> scalar
__global__ void k_final(const int* __restrict__ mip, const int* __restrict__ cnt,
                        const int* __restrict__ slot1, const int* __restrict__ E2,
                        const float* __restrict__ gb,
                        const float* __restrict__ as2, const float* __restrict__ ad2,
                        const float* __restrict__ b2,
                        const float* __restrict__ r1,
                        const float* __restrict__ Wm2, const float* __restrict__ bm2,
                        const float* __restrict__ Wp1, const float* __restrict__ bp1,
                        const float* __restrict__ Wp2, const float* __restrict__ bp2,
                        const float* __restrict__ Wp3, const float* __restrict__ bp3,
                        float* __restrict__ out){
  __shared__ float al[MAXE2];
  __shared__ int   jl[MAXE2];
  __shared__ float feat[C2], r2s[C2], z1s[C2], z2s[32];
  int t = threadIdx.x;
  int mi  = mip[0];
  int jmi = slot1[mi];
  int ne2 = cnt[3]; if (ne2 > MAXE2) ne2 = MAXE2;
  for (int k = t; k < ne2; k += 256) jl[k] = slot1[E2[k]];
  __syncthreads();
  int w = t >> 6, lane = t & 63;
  float adv;
  {
    int c = lane * 2;
    float v = gb[jmi * C2 + c] * ad2[c] + gb[jmi * C2 + c + 1] * ad2[c + 1];
    #pragma unroll
    for (int o = 32; o; o >>= 1) v += __shfl_xor(v, o, 64);
    adv = v;
  }
  for (int k = w; k < ne2; k += 4){
    int c = lane * 2;
    int jj = jl[k];
    float v = gb[jj * C2 + c] * as2[c] + gb[jj * C2 + c + 1] * as2[c + 1];
    #pragma unroll
    for (int o = 32; o; o >>= 1) v += __shfl_xor(v, o, 64);
    if (lane == 0) al[k] = lrelu(v + adv);
  }
  __syncthreads();
  if (t < 64){
    float m = -3.4e38f;
    for (int k = t; k < ne2; k += 64) m = fmaxf(m, al[k]);
    #pragma unroll
    for (int o = 32; o; o >>= 1) m = fmaxf(m, __shfl_xor(m, o, 64));
    float s = 0.f;
    for (int k = t; k < ne2; k += 64){
      float a2 = expf(al[k] - m);
      al[k] = a2;
      s += a2;
    }
    #pragma unroll
    for (int o = 32; o; o >>= 1) s += __shfl_xor(s, o, 64);
    float inv = 1.f / (s + 1e-16f);
    for (int k = t; k < ne2; k += 64) al[k] *= inv;
  }
  __syncthreads();
  if (t < C2){
    float acc = 0.f;
    for (int k = 0; k < ne2; ++k) acc += al[k] * gb[jl[k] * C2 + t];
    float v = acc + b2[t];
    feat[t] = v > 0.f ? v : 0.f;
    float pr = 0.f;
    for (int k = 0; k < C2; ++k) pr += r1[k] * Wm2[k * C2 + t];
    r2s[t] = pr + bm2[t];
  }
  __syncthreads();
  if (t < C2){
    float acc = 0.f;
    for (int k = 0; k < C2; ++k) acc += feat[k] * Wp1[k * C2 + t];
    for (int k = 0; k < C2; ++k) acc += r2s[k] * Wp1[(C2 + k) * C2 + t];
    float v = acc + bp1[t];
    z1s[t] = v > 0.f ? v : 0.f;
  }
  __syncthreads();
  if (t < 32){
    float acc = 0.f;
    for (int k = 0; k < C2; ++k) acc += z1s[k] * Wp2[k * 32 + t];
    float v = acc + bp2[t];
    z2s[t] = v > 0.f ? v : 0.f;
  }
  __syncthreads();
  if (t == 0){
    float acc = 0.f;
    for (int k = 0; k < 32; ++k) acc += z2s[k] * Wp3[k];
    out[0] = acc + bp3[0];
  }
}

extern "C" void kernel_launch(void* const* d_in, const int* in_sizes, int n_in,
                              void* d_out, int out_size, void* d_ws, size_t ws_size,
                              hipStream_t stream){
  const float* x   = (const float*)d_in[0];
  const int*   ei  = (const int*)d_in[1];
  const int*   mip = (const int*)d_in[2];
  const float* msd = (const float*)d_in[3];
  const float* Wm1 = (const float*)d_in[4];
  const float* bm1 = (const float*)d_in[5];
  const float* Wm2 = (const float*)d_in[6];
  const float* bm2 = (const float*)d_in[7];
  const float* W1  = (const float*)d_in[8];
  const float* as1 = (const float*)d_in[9];
  const float* ad1 = (const float*)d_in[10];
  const float* b1  = (const float*)d_in[11];
  const float* W2  = (const float*)d_in[12];
  const float* as2 = (const float*)d_in[13];
  const float* ad2 = (const float*)d_in[14];
  const float* b2  = (const float*)d_in[15];
  const float* Wp1 = (const float*)d_in[16];
  const float* bp1 = (const float*)d_in[17];
  const float* Wp2 = (const float*)d_in[18];
  const float* bp2 = (const float*)d_in[19];
  const float* Wp3 = (const float*)d_in[20];
  const float* bp3 = (const float*)d_in[21];
  float* out = (float*)d_out;

  char* q = (char*)d_ws;
  auto alloc = [&](size_t bytes) -> void* {
    void* r = (void*)q;
    q += (bytes + 255) & ~(size_t)255;
    return r;
  };
  int* cnt   = (int*)alloc(8 * 4);
  int* slot1 = (int*)alloc(NNODES * 4);
  int* slot2 = (int*)alloc(NNODES * 4);
  int* S1    = (int*)alloc(MAX1 * 4);
  int* S2    = (int*)alloc(MAX2 * 4);
  int* E1s   = (int*)alloc(MAXE1 * 4);
  int* E1d   = (int*)alloc(MAXE1 * 4);
  int* E2    = (int*)alloc(MAXE2 * 4);
  float* hpart = (float*)alloc((size_t)NKC * MAX2 * FH * 4);   // 41.9 MB (ws ~400 MB)
  float* hh    = (float*)alloc((size_t)MAX2 * FH * 4);         // 2 MB
  float* gb    = (float*)alloc(MAX1 * C2 * 4);
  float* asrc1 = (float*)alloc(MAX2 * NHEAD * 4);
  float* adst1 = (float*)alloc(MAX2 * NHEAD * 4);
  float* r1    = (float*)alloc(C2 * 4);

  k_init <<<(NNODES + 255) / 256, 256, 0, stream>>>(cnt, slot1, slot2);
  k_scan1<<<(NE_TOT + 255) / 256, 256, 0, stream>>>(ei, mip, cnt, slot1, S1, E2);
  k_scan2<<<(NE_TOT + 255) / 256, 256, 0, stream>>>(ei, cnt, slot1, slot2, S2, E1s, E1d);
  k_hh   <<<HH_GEMM_BLOCKS + 4, 256, 0, stream>>>(x, W1, msd, Wm1, bm1, cnt, S2, hpart, r1);
  k_ascal<<<128, 256, 0, stream>>>(hpart, as1, ad1, cnt, hh, asrc1, adst1);
  k_agg1 <<<32, 256, 0, stream>>>(hh, asrc1, adst1, b1, W2, cnt, S1, slot2, E1s, E1d, gb);
  k_final<<<1, 256, 0, stream>>>(mip, cnt, slot1, E2, gb, as2, ad2, b2, r1,
                                 Wm2, bm2, Wp1, bp1, Wp2, bp2, Wp3, bp3, out);
}

// Round 6
// 67.418 us; speedup vs baseline: 4.2250x; 1.2791x over previous
//
#include <hip/hip_runtime.h>
#include <hip/hip_bf16.h>

#define NNODES 20000
#define NE_RAW 200000
#define NE_TOT 220000
#define MAX1   128
#define MAX2   512
#define MAXE1  4096
#define MAXE2  256
#define FIN    1280
#define FH     1024
#define HC     256
#define NHEAD  4
#define C2     128
#define CAPE   512
#define KCK    64       // k per chunk
#define NKC    20       // 20 x 64 = 1280
#define HH_GEMM_BLOCKS 320   // 20 kc x 8 ct x 2 row-splits

__device__ __forceinline__ float lrelu(float x){ return x >= 0.f ? x : 0.2f * x; }

// K0: reset slot maps + counters
__global__ void k_init(int* cnt, int* slot1, int* slot2){
  int i = blockIdx.x * 256 + threadIdx.x;
  if (i < NNODES){ slot1[i] = -1; slot2[i] = -1; }
  if (i < 8) cnt[i] = 0;
}

// K1: S1 = in-neighbors of mutation_idx (incl. self-loop), E2 = edges into mi
__global__ void k_scan1(const int* __restrict__ ei, const int* __restrict__ mip,
                        int* cnt, int* slot1, int* S1, int* E2){
  int e = blockIdx.x * 256 + threadIdx.x;
  if (e >= NE_TOT) return;
  int mi = mip[0];
  int src, dst;
  if (e < NE_RAW){ src = ei[e]; dst = ei[NE_RAW + e]; }
  else { src = e - NE_RAW; dst = src; }
  if (dst != mi) return;
  int p = atomicAdd(&cnt[3], 1);
  if (p < MAXE2) E2[p] = src;
  if (atomicCAS(&slot1[src], -1, -9) == -1){
    int idx = atomicAdd(&cnt[0], 1);
    if (idx < MAX1){ S1[idx] = src; slot1[src] = idx; }
  }
}

// K2: S2 = in-neighbors of S1; E1 = edge occurrences into S1
__global__ void k_scan2(const int* __restrict__ ei, int* cnt,
                        const int* __restrict__ slot1, int* slot2,
                        int* S2, int* E1s, int* E1d){
  int e = blockIdx.x * 256 + threadIdx.x;
  if (e >= NE_TOT) return;
  int src, dst;
  if (e < NE_RAW){ src = ei[e]; dst = ei[NE_RAW + e]; }
  else { src = e - NE_RAW; dst = src; }
  if (slot1[dst] < 0) return;
  int p = atomicAdd(&cnt[2], 1);
  if (p < MAXE1){ E1s[p] = src; E1d[p] = dst; }
  if (atomicCAS(&slot2[src], -1, -9) == -1){
    int idx = atomicAdd(&cnt[1], 1);
    if (idx < MAX2){ S2[idx] = src; slot2[src] = idx; }
  }
}

// K3: LDS-tiled pruned GEMM (unchanged from R5). Block = (kc, ct, rs).
__global__ __launch_bounds__(256) void k_hh(
    const float* __restrict__ x, const float* __restrict__ W1,
    const float* __restrict__ msd, const float* __restrict__ Wm1,
    const float* __restrict__ bm1,
    const int* __restrict__ cnt, const int* __restrict__ S2,
    float* __restrict__ hpart, float* __restrict__ r1){
  int t = threadIdx.x;
  if (blockIdx.x >= HH_GEMM_BLOCKS){
    __shared__ float red[256];
    int b   = blockIdx.x - HH_GEMM_BLOCKS;   // 0..3 -> 32 cols each
    int col = b * 32 + (t & 31);
    int sl  = t >> 5;                        // 8 k-slices of 128
    float s = 0.f;
    for (int k = sl * 128; k < sl * 128 + 128; ++k)
      s += msd[k] * Wm1[k * C2 + col];
    red[t] = s;
    __syncthreads();
    if (t < 32){
      float v = 0.f;
      #pragma unroll
      for (int q = 0; q < 8; ++q) v += red[q * 32 + t];
      v += bm1[col];
      r1[col] = v > 0.f ? v : 0.f;
    }
    return;
  }
  __shared__ float Wl[KCK][128];   // 32 KB
  __shared__ float Xl[KCK][32];    // 8 KB, transposed: [k][row]
  int bid = blockIdx.x;
  int rs = bid & 1, ct = (bid >> 1) & 7, kc = bid >> 4;
  int k0 = kc * KCK, c0 = ct * 128;
  int n2 = cnt[1]; if (n2 > MAX2) n2 = MAX2;
  for (int idx = t; idx < 2048; idx += 256){
    int r = idx >> 5, c4 = idx & 31;
    *(float4*)&Wl[r][c4 * 4] = *(const float4*)(W1 + (long)(k0 + r) * FH + c0 + c4 * 4);
  }
  int nRG = (n2 + 31) >> 5;
  int cth = t & 31, rth = t >> 5;
  for (int rg = rs; rg < nRG; rg += 2){
    int r0 = rg * 32;
    __syncthreads();
    for (int idx = t; idx < 512; idx += 256){
      int r = idx & 31, kq = idx >> 5;
      float4 v = make_float4(0.f, 0.f, 0.f, 0.f);
      if (r0 + r < n2)
        v = *(const float4*)(x + (long)S2[r0 + r] * FIN + k0 + kq * 4);
      Xl[kq * 4 + 0][r] = v.x;
      Xl[kq * 4 + 1][r] = v.y;
      Xl[kq * 4 + 2][r] = v.z;
      Xl[kq * 4 + 3][r] = v.w;
    }
    __syncthreads();
    float4 a0 = make_float4(0.f,0.f,0.f,0.f), a1 = a0, a2 = a0, a3 = a0;
    #pragma unroll 4
    for (int k = 0; k < KCK; ++k){
      float4 w  = *(const float4*)&Wl[k][cth * 4];
      float4 xv = *(const float4*)&Xl[k][rth * 4];
      a0.x += xv.x * w.x; a0.y += xv.x * w.y; a0.z += xv.x * w.z; a0.w += xv.x * w.w;
      a1.x += xv.y * w.x; a1.y += xv.y * w.y; a1.z += xv.y * w.z; a1.w += xv.y * w.w;
      a2.x += xv.z * w.x; a2.y += xv.z * w.y; a2.z += xv.z * w.z; a2.w += xv.z * w.w;
      a3.x += xv.w * w.x; a3.y += xv.w * w.y; a3.z += xv.w * w.z; a3.w += xv.w * w.w;
    }
    int rb = r0 + rth * 4;
    float* dp = hpart + ((long)kc * MAX2 + rb) * FH + c0 + cth * 4;
    if (rb + 0 < n2) *(float4*)(dp)            = a0;
    if (rb + 1 < n2) *(float4*)(dp + FH)       = a1;
    if (rb + 2 < n2) *(float4*)(dp + 2L * FH)  = a2;
    if (rb + 3 < n2) *(float4*)(dp + 3L * FH)  = a3;
  }
}

// K4: hh = sum_kc hpart ; attention scalars asrc1/adst1 (one block per S2 row)
__global__ void k_ascal(const float* __restrict__ hpart,
                        const float* __restrict__ as1, const float* __restrict__ ad1,
                        const int* __restrict__ cnt,
                        float* __restrict__ hh,
                        float* __restrict__ asrc1, float* __restrict__ adst1){
  int t = threadIdx.x, head = t >> 6;
  int n2 = cnt[1]; if (n2 > MAX2) n2 = MAX2;
  float4 a = *(const float4*)(as1 + 4 * t);
  float4 d = *(const float4*)(ad1 + 4 * t);
  for (int i = blockIdx.x; i < n2; i += gridDim.x){
    float4 s = make_float4(0.f, 0.f, 0.f, 0.f);
    #pragma unroll
    for (int kc = 0; kc < NKC; ++kc){
      float4 v = *(const float4*)(hpart + ((long)kc * MAX2 + i) * FH + 4 * t);
      s.x += v.x; s.y += v.y; s.z += v.z; s.w += v.w;
    }
    *(float4*)(hh + (long)i * FH + 4 * t) = s;
    float ss = s.x * a.x + s.y * a.y + s.z * a.z + s.w * a.w;
    float sd = s.x * d.x + s.y * d.y + s.z * d.z + s.w * d.w;
    #pragma unroll
    for (int o = 32; o; o >>= 1){ ss += __shfl_xor(ss, o, 64); sd += __shfl_xor(sd, o, 64); }
    if ((t & 63) == 0){ asrc1[i * NHEAD + head] = ss; adst1[i * NHEAD + head] = sd; }
  }
}

// K5: per S1-node (1024 threads): softmax + aggregate -> h1row -> k-split GEMV -> gb
__global__ __launch_bounds__(1024) void k_agg1(
    const float* __restrict__ hh,
    const float* __restrict__ asrc1, const float* __restrict__ adst1,
    const float* __restrict__ b1, const float* __restrict__ W2,
    const int* __restrict__ cnt, const int* __restrict__ S1,
    const int* __restrict__ slot2,
    const int* __restrict__ E1s, const int* __restrict__ E1d,
    float* __restrict__ gb){
  __shared__ int   lsrc[CAPE];
  __shared__ float ev[NHEAD][CAPE];
  __shared__ float h1row[FH];
  __shared__ float part[8][C2];
  __shared__ int   scnt;
  int t = threadIdx.x;
  int n1  = cnt[0]; if (n1  > MAX1)  n1  = MAX1;
  int nE1 = cnt[2]; if (nE1 > MAXE1) nE1 = MAXE1;
  for (int j = blockIdx.x; j < n1; j += gridDim.x){
    int s = S1[j];
    __syncthreads();
    if (t == 0) scnt = 0;
    __syncthreads();
    for (int e = t; e < nE1; e += 1024){
      if (E1d[e] == s){
        int q = atomicAdd(&scnt, 1);
        if (q < CAPE) lsrc[q] = slot2[E1s[e]];
      }
    }
    __syncthreads();
    int ce = scnt; if (ce > CAPE) ce = CAPE;
    if (t < 256){
      int w = t >> 6, lane = t & 63;
      float ad = adst1[slot2[s] * NHEAD + w];
      float m = -3.4e38f;
      for (int e = lane; e < ce; e += 64){
        float v = lrelu(asrc1[lsrc[e] * NHEAD + w] + ad);
        ev[w][e] = v;
        m = fmaxf(m, v);
      }
      #pragma unroll
      for (int o = 32; o; o >>= 1) m = fmaxf(m, __shfl_xor(m, o, 64));
      float ssum = 0.f;
      for (int e = lane; e < ce; e += 64){
        float a2 = expf(ev[w][e] - m);
        ev[w][e] = a2;
        ssum += a2;
      }
      #pragma unroll
      for (int o = 32; o; o >>= 1) ssum += __shfl_xor(ssum, o, 64);
      float inv = 1.f / (ssum + 1e-16f);
      for (int e = lane; e < ce; e += 64) ev[w][e] *= inv;
    }
    __syncthreads();
    if (t < 256){
      int hd = t >> 6;
      float4 accv = make_float4(0.f, 0.f, 0.f, 0.f);
      int e = 0;
      for (; e + 3 < ce; e += 4){
        float al0 = ev[hd][e],     al1 = ev[hd][e + 1];
        float al2 = ev[hd][e + 2], al3 = ev[hd][e + 3];
        float4 h0 = *(const float4*)(hh + (long)lsrc[e]     * FH + 4 * t);
        float4 h1 = *(const float4*)(hh + (long)lsrc[e + 1] * FH + 4 * t);
        float4 h2 = *(const float4*)(hh + (long)lsrc[e + 2] * FH + 4 * t);
        float4 h3 = *(const float4*)(hh + (long)lsrc[e + 3] * FH + 4 * t);
        accv.x += al0 * h0.x + al1 * h1.x + al2 * h2.x + al3 * h3.x;
        accv.y += al0 * h0.y + al1 * h1.y + al2 * h2.y + al3 * h3.y;
        accv.z += al0 * h0.z + al1 * h1.z + al2 * h2.z + al3 * h3.z;
        accv.w += al0 * h0.w + al1 * h1.w + al2 * h2.w + al3 * h3.w;
      }
      for (; e < ce; ++e){
        float al0 = ev[hd][e];
        float4 h0 = *(const float4*)(hh + (long)lsrc[e] * FH + 4 * t);
        accv.x += al0 * h0.x; accv.y += al0 * h0.y;
        accv.z += al0 * h0.z; accv.w += al0 * h0.w;
      }
      float4 bv = *(const float4*)(b1 + 4 * t);
      accv.x += bv.x; accv.y += bv.y; accv.z += bv.z; accv.w += bv.w;
      accv.x = accv.x > 0.f ? accv.x : 0.f;
      accv.y = accv.y > 0.f ? accv.y : 0.f;
      accv.z = accv.z > 0.f ? accv.z : 0.f;
      accv.w = accv.w > 0.f ? accv.w : 0.f;
      *(float4*)(h1row + 4 * t) = accv;
    }
    __syncthreads();
    // GEMV h1row @ W2: 128 cols x 8 k-slices of 128
    {
      int col = t & 127, sl = t >> 7;
      const float* Wp = W2 + (long)(sl * 128) * C2 + col;
      const float* hp = h1row + sl * 128;
      float g = 0.f;
      #pragma unroll 16
      for (int k = 0; k < 128; ++k) g += hp[k] * Wp[(long)k * C2];
      part[sl][col] = g;
    }
    __syncthreads();
    if (t < C2){
      float s8 = 0.f;
      #pragma unroll
      for (int q = 0; q < 8; ++q) s8 += part[q][t];
      gb[j * C2 + t] = s8;
    }
  }
}

// K6 (512 threads): layer-2 attention + softmax + aggregate at mi, k-split MLP head
__global__ __launch_bounds__(512) void k_final(
    const int* __restrict__ mip, const int* __restrict__ cnt,
    const int* __restrict__ slot1, const int* __restrict__ E2,
    const float* __restrict__ gb,
    const float* __restrict__ as2, const float* __restrict__ ad2,
    const float* __restrict__ b2,
    const float* __restrict__ r1,
    const float* __restrict__ Wm2, const float* __restrict__ bm2,
    const float* __restrict__ Wp1, const float* __restrict__ bp1,
    const float* __restrict__ Wp2, const float* __restrict__ bp2,
    const float* __restrict__ Wp3, const float* __restrict__ bp3,
    float* __restrict__ out){
  __shared__ float al[MAXE2];
  __shared__ int   jl[MAXE2];
  __shared__ float feat[C2], r2s[C2], z1s[C2], z2s[32];
  __shared__ float p4[4][C2];
  __shared__ float p16[16][32];
  int t = threadIdx.x;
  int mi  = mip[0];
  int jmi = slot1[mi];
  int ne2 = cnt[3]; if (ne2 > MAXE2) ne2 = MAXE2;
  for (int k = t; k < ne2; k += 512) jl[k] = slot1[E2[k]];
  __syncthreads();
  int w = t >> 6, lane = t & 63;
  // logits: each wave computes adv then strides edges (8 waves)
  {
    int c = lane * 2;
    float v = gb[jmi * C2 + c] * ad2[c] + gb[jmi * C2 + c + 1] * ad2[c + 1];
    #pragma unroll
    for (int o = 32; o; o >>= 1) v += __shfl_xor(v, o, 64);
    float adv = v;
    for (int k = w; k < ne2; k += 8){
      int jj = jl[k];
      float u = gb[jj * C2 + c] * as2[c] + gb[jj * C2 + c + 1] * as2[c + 1];
      #pragma unroll
      for (int o = 32; o; o >>= 1) u += __shfl_xor(u, o, 64);
      if (lane == 0) al[k] = lrelu(u + adv);
    }
  }
  __syncthreads();
  if (t < 64){
    float m = -3.4e38f;
    for (int k = t; k < ne2; k += 64) m = fmaxf(m, al[k]);
    #pragma unroll
    for (int o = 32; o; o >>= 1) m = fmaxf(m, __shfl_xor(m, o, 64));
    float s = 0.f;
    for (int k = t; k < ne2; k += 64){
      float a2 = expf(al[k] - m);
      al[k] = a2;
      s += a2;
    }
    #pragma unroll
    for (int o = 32; o; o >>= 1) s += __shfl_xor(s, o, 64);
    float inv = 1.f / (s + 1e-16f);
    for (int k = t; k < ne2; k += 64) al[k] *= inv;
  }
  __syncthreads();
  int col = t & 127, sub = t >> 7;                 // sub in 0..3
  // r2s partials (4 k-slices of 32) ; feat on t<128 in parallel
  {
    float pr = 0.f;
    #pragma unroll 8
    for (int k = sub * 32; k < sub * 32 + 32; ++k) pr += r1[k] * Wm2[k * C2 + col];
    p4[sub][col] = pr;
    if (t < C2){
      float acc = 0.f;
      for (int k = 0; k < ne2; ++k) acc += al[k] * gb[jl[k] * C2 + t];
      float v = acc + b2[t];
      feat[t] = v > 0.f ? v : 0.f;
    }
  }
  __syncthreads();
  if (t < C2) r2s[t] = p4[0][t] + p4[1][t] + p4[2][t] + p4[3][t] + bm2[t];
  __syncthreads();
  // z1 partials: 4 k-slices of 64 over [feat | r2s]
  {
    float acc = 0.f;
    #pragma unroll 8
    for (int k = sub * 64; k < sub * 64 + 64; ++k){
      float zv = (k < C2) ? feat[k] : r2s[k - C2];
      acc += zv * Wp1[k * C2 + col];
    }
    p4[sub][col] = acc;
  }
  __syncthreads();
  if (t < C2){
    float v = p4[0][t] + p4[1][t] + p4[2][t] + p4[3][t] + bp1[t];
    z1s[t] = v > 0.f ? v : 0.f;
  }
  __syncthreads();
  // z2 partials: 32 cols x 16 k-slices of 8
  {
    int c2 = t & 31, sl = t >> 5;
    float acc = 0.f;
    #pragma unroll
    for (int k = sl * 8; k < sl * 8 + 8; ++k) acc += z1s[k] * Wp2[k * 32 + c2];
    p16[sl][c2] = acc;
  }
  __syncthreads();
  if (t < 32){
    float s = 0.f;
    #pragma unroll
    for (int q = 0; q < 16; ++q) s += p16[q][t];
    float v = s + bp2[t];
    z2s[t] = v > 0.f ? v : 0.f;
  }
  __syncthreads();
  if (t == 0){
    float acc = 0.f;
    for (int k = 0; k < 32; ++k) acc += z2s[k] * Wp3[k];
    out[0] = acc + bp3[0];
  }
}

extern "C" void kernel_launch(void* const* d_in, const int* in_sizes, int n_in,
                              void* d_out, int out_size, void* d_ws, size_t ws_size,
                              hipStream_t stream){
  const float* x   = (const float*)d_in[0];
  const int*   ei  = (const int*)d_in[1];
  const int*   mip = (const int*)d_in[2];
  const float* msd = (const float*)d_in[3];
  const float* Wm1 = (const float*)d_in[4];
  const float* bm1 = (const float*)d_in[5];
  const float* Wm2 = (const float*)d_in[6];
  const float* bm2 = (const float*)d_in[7];
  const float* W1  = (const float*)d_in[8];
  const float* as1 = (const float*)d_in[9];
  const float* ad1 = (const float*)d_in[10];
  const float* b1  = (const float*)d_in[11];
  const float* W2  = (const float*)d_in[12];
  const float* as2 = (const float*)d_in[13];
  const float* ad2 = (const float*)d_in[14];
  const float* b2  = (const float*)d_in[15];
  const float* Wp1 = (const float*)d_in[16];
  const float* bp1 = (const float*)d_in[17];
  const float* Wp2 = (const float*)d_in[18];
  const float* bp2 = (const float*)d_in[19];
  const float* Wp3 = (const float*)d_in[20];
  const float* bp3 = (const float*)d_in[21];
  float* out = (float*)d_out;

  char* q = (char*)d_ws;
  auto alloc = [&](size_t bytes) -> void* {
    void* r = (void*)q;
    q += (bytes + 255) & ~(size_t)255;
    return r;
  };
  int* cnt   = (int*)alloc(8 * 4);
  int* slot1 = (int*)alloc(NNODES * 4);
  int* slot2 = (int*)alloc(NNODES * 4);
  int* S1    = (int*)alloc(MAX1 * 4);
  int* S2    = (int*)alloc(MAX2 * 4);
  int* E1s   = (int*)alloc(MAXE1 * 4);
  int* E1d   = (int*)alloc(MAXE1 * 4);
  int* E2    = (int*)alloc(MAXE2 * 4);
  float* hpart = (float*)alloc((size_t)NKC * MAX2 * FH * 4);   // 41.9 MB
  float* hh    = (float*)alloc((size_t)MAX2 * FH * 4);         // 2 MB
  float* gb    = (float*)alloc(MAX1 * C2 * 4);
  float* asrc1 = (float*)alloc(MAX2 * NHEAD * 4);
  float* adst1 = (float*)alloc(MAX2 * NHEAD * 4);
  float* r1    = (float*)alloc(C2 * 4);

  k_init <<<(NNODES + 255) / 256, 256, 0, stream>>>(cnt, slot1, slot2);
  k_scan1<<<(NE_TOT + 255) / 256, 256, 0, stream>>>(ei, mip, cnt, slot1, S1, E2);
  k_scan2<<<(NE_TOT + 255) / 256, 256, 0, stream>>>(ei, cnt, slot1, slot2, S2, E1s, E1d);
  k_hh   <<<HH_GEMM_BLOCKS + 4, 256, 0, stream>>>(x, W1, msd, Wm1, bm1, cnt, S2, hpart, r1);
  k_ascal<<<128, 256, 0, stream>>>(hpart, as1, ad1, cnt, hh, asrc1, adst1);
  k_agg1 <<<32, 1024, 0, stream>>>(hh, asrc1, adst1, b1, W2, cnt, S1, slot2, E1s, E1d, gb);
  k_final<<<1, 512, 0, stream>>>(mip, cnt, slot1, E2, gb, as2, ad2, b2, r1,
                                 Wm2, bm2, Wp1, bp1, Wp2, bp2, Wp3, bp3, out);
}